// Round 9
// baseline (266.399 us; speedup 1.0000x reference)
//
#include <hip/hip_runtime.h>
#include <hip/hip_bf16.h>

typedef unsigned short u16;
typedef unsigned int   u32;
typedef short  short8v __attribute__((ext_vector_type(8)));
typedef u16    u16x8   __attribute__((ext_vector_type(8)));
typedef float  f32x16  __attribute__((ext_vector_type(16)));
typedef float  f32x4v  __attribute__((ext_vector_type(4)));
typedef u32    u32x2   __attribute__((ext_vector_type(2)));
typedef u32    u32x4   __attribute__((ext_vector_type(4)));

#define HEADS 64
#define DMODEL 128
#define SEQ 2048

// log2(e)/sqrt(128), folded into Qt during prep
#define SCQ 0.1275293f
// P-buffer row stride in u16 (160B)
#define PSTR 80

// ---------- helpers ----------

__device__ __forceinline__ f32x16 mfma_bf16(short8v a, short8v b, f32x16 c) {
  return __builtin_amdgcn_mfma_f32_32x32x16_bf16(a, b, c, 0, 0, 0);
}

__device__ __forceinline__ f32x16 fzero16() {
  f32x16 z;
#pragma unroll
  for (int i = 0; i < 16; ++i) z[i] = 0.f;
  return z;
}

__device__ __forceinline__ float fast_exp2(float x) {
  float r;
  asm("v_exp_f32 %0, %1" : "=v"(r) : "v"(x));   // v_exp_f32 IS exp2
  return r;
}

// round-to-nearest-even f32 -> bf16 bits
__device__ __forceinline__ u32 bfround(float x) {
  u32 u = __builtin_bit_cast(u32, x);
  u += 0x7fffu + ((u >> 16) & 1u);
  return u >> 16;
}
__device__ __forceinline__ u32 bfpair(float lo, float hi) {
  u32 a = __builtin_bit_cast(u32, lo); a += 0x7fffu + ((a >> 16) & 1u);
  u32 b = __builtin_bit_cast(u32, hi); b += 0x7fffu + ((b >> 16) & 1u);
  return (a >> 16) | (b & 0xffff0000u);
}
// hot-loop pack -> v_cvt_pk_bf16_f32 via compiler (m240)
__device__ __forceinline__ u32 packbf(float lo, float hi) {
  u32 l16 = (u32)__builtin_bit_cast(u16, __float2bfloat16(lo));
  u32 h16 = (u32)__builtin_bit_cast(u16, __float2bfloat16(hi));
  return l16 | (h16 << 16);
}

// async global->LDS, 16B/lane, dest = wave-uniform base + lane*16
typedef const __attribute__((address_space(1))) void* gp1_t;
typedef __attribute__((address_space(3))) void* lp3_t;
__device__ __forceinline__ void gload16(const u16* g, u16* l) {
  __builtin_amdgcn_global_load_lds((gp1_t)g, (lp3_t)l, 16, 0, 0);
}

// K-prologue transposing stage (first 512 threads): src [128 d][2048 pos] f32 ->
// LDS tile [64 pos][128 d] bf16, chunk' = chunk ^ (row & 15)
__device__ __forceinline__ void stage_T(const float* __restrict__ src, int pos0,
                                        u16* lds, int tid) {
  int ic = tid & 7;
  int d0 = (tid >> 3) * 2;
  const float* p = src + d0 * SEQ + pos0 + ic * 8;
  f32x4v xa = *reinterpret_cast<const f32x4v*>(p);
  f32x4v xb = *reinterpret_cast<const f32x4v*>(p + 4);
  f32x4v ya = *reinterpret_cast<const f32x4v*>(p + SEQ);
  f32x4v yb = *reinterpret_cast<const f32x4v*>(p + SEQ + 4);
  u32* lds32 = reinterpret_cast<u32*>(lds);
  int cc = d0 >> 3;
#pragma unroll
  for (int k = 0; k < 8; ++k) {
    int r = ic * 8 + k;
    int c2 = cc ^ (r & 15);
    float xv = (k < 4) ? xa[k & 3] : xb[k & 3];
    float yv = (k < 4) ? ya[k & 3] : yb[k & 3];
    lds32[(r * 128 + c2 * 8 + (d0 & 7)) >> 1] = bfpair(xv, yv);
  }
}

// fragment reads (ds_read_b128), undoing the XOR swizzles
__device__ __forceinline__ short8v ld_at(const u16* lds, int row, int chunk) {
  return *reinterpret_cast<const short8v*>(lds + row * 128 + ((chunk ^ (row & 15)) * 8));
}
__device__ __forceinline__ short8v ld_vt(const u16* lds, int d, int chunk) {
  return *reinterpret_cast<const short8v*>(lds + d * 64 + ((chunk ^ (d & 7)) * 8));
}

// ---------- fused prep kernel ----------
__global__ __launch_bounds__(256) void prep_kernel(
    const float* __restrict__ Q, const float* __restrict__ V,
    const float* __restrict__ Wsrc, u16* __restrict__ Qt,
    u16* __restrict__ V16t, u16* __restrict__ Wt) {
  int blk = blockIdx.x;
  int t = threadIdx.x;
  if (blk < 2048) {
    int n = blk >> 5, pt = blk & 31;
    const float* src = Q + (size_t)n * DMODEL * SEQ;
    u16* dst = Qt + (size_t)n * SEQ * DMODEL + (size_t)pt * 64 * DMODEL;
    int pq = t & 15, dq = t >> 4;
#pragma unroll
    for (int p = 0; p < 2; ++p) {
      int d0 = (dq + 16 * p) * 4;
      const float* s0 = src + (size_t)d0 * SEQ + pt * 64 + pq * 4;
      f32x4v r0 = *reinterpret_cast<const f32x4v*>(s0);
      f32x4v r1 = *reinterpret_cast<const f32x4v*>(s0 + SEQ);
      f32x4v r2 = *reinterpret_cast<const f32x4v*>(s0 + 2 * SEQ);
      f32x4v r3 = *reinterpret_cast<const f32x4v*>(s0 + 3 * SEQ);
#pragma unroll
      for (int j = 0; j < 4; ++j) {
        u32x2 v = { bfpair(r0[j] * SCQ, r1[j] * SCQ), bfpair(r2[j] * SCQ, r3[j] * SCQ) };
        *reinterpret_cast<u32x2*>(dst + (pq * 4 + j) * DMODEL + d0) = v;
      }
    }
  } else if (blk < 4096) {
    int b2 = blk - 2048;
    int n = b2 >> 5, it = b2 & 31;
    int s8 = (t & 7) * 8;
    const float* src = V + (size_t)n * DMODEL * SEQ + it * 64 + s8;
    u16* dst = V16t + (size_t)b2 * DMODEL * 64 + s8;
#pragma unroll
    for (int rr = 0; rr < 4; ++rr) {
      int d = (t >> 3) + 32 * rr;
      const float* p = src + (size_t)d * SEQ;
      f32x4v a = *reinterpret_cast<const f32x4v*>(p);
      f32x4v b = *reinterpret_cast<const f32x4v*>(p + 4);
      u32x4 v = { bfpair(a[0], a[1]), bfpair(a[2], a[3]),
                  bfpair(b[0], b[1]), bfpair(b[2], b[3]) };
      *reinterpret_cast<u32x4*>(dst + d * 64) = v;
    }
  } else {
    int e = (blk - 4096) * 256 + t;
#pragma unroll
    for (int rr = 0; rr < 2; ++rr) {
      int o = e + rr * 131072;
      int dm = o >> 11, c = o & 2047;
      Wt[o] = (u16)bfround(Wsrc[c * 128 + dm]);
    }
  }
}

// ---------- flash attention, dual-j-tile wave specialization ----------
// 512 blocks = head(64) x jblock(8 x 256 j), head%8 -> XCD. 768 thr = 12 waves:
//   w 0-3  producers: 2 j-tiles each {tile w, tile w+4}, i in 32-sub-tiles
//   w 4-11 consumers: 64 j (tiles {2u,2u+1}, u=(w-4)&3) x 64 d (half (w-4)>>2)
// Each A-read and V-read feeds 2 MFMAs (dual-j reuse). Per-sub alpha keeps
// online softmax exact across the two 32-i halves of each 64-i staged tile.
__global__ __launch_bounds__(768, 3) void attn_kernel(
    const u16* __restrict__ Qt, const float* __restrict__ K,
    const u16* __restrict__ V16t, u16* __restrict__ Ows) {
  __shared__ __align__(16) u16 AT2[2][64 * DMODEL];    // 2x16KB Q tiles
  __shared__ __align__(16) u16 VT2[2][DMODEL * 64];    // 2x16KB V tiles
  __shared__ __align__(16) u16 PB[2][256 * PSTR];      // 2x40KB P tiles
  __shared__ float AL[2][2][256];                      // alpha per (buf, sub, j)
  __shared__ float LL[256];                            // final l per j
  const int tid = threadIdx.x;
  const int w = tid >> 6;
  const int lane = tid & 63;
  const int g = lane >> 5;
  const int lj = lane & 31;
  const int p_ = blockIdx.x;
  const int n = ((p_ >> 6) << 3) | (p_ & 7);
  const int j0 = ((p_ >> 3) & 7) * 256;
  const u16* Qtn = Qt + (size_t)n * SEQ * DMODEL;
  const float* Kb = K + (size_t)n * DMODEL * SEQ;
  const u16* Vtn = V16t + (size_t)n * 32 * DMODEL * 64;

  // staging lane offsets: producers 4 gload16/tile, consumers 2 gload16/tile
  int qoff[4];
#pragma unroll
  for (int i = 0; i < 4; ++i) {
    int idx = (w & 3) * 4 + i;
    int pos = idx * 4 + (lane >> 4);
    qoff[i] = pos * DMODEL + (((lane & 15) ^ (pos & 15)) * 8);
  }
  int voff[2];
#pragma unroll
  for (int i = 0; i < 2; ++i) {
    int idx = ((w - 4) & 7) * 2 + i;
    int d = idx * 8 + (lane >> 3);
    voff[i] = d * 64 + (((lane & 7) ^ (d & 7)) * 8);
  }

  // prime A(0)
  if (w < 4) {
#pragma unroll
    for (int i = 0; i < 4; ++i)
      gload16(Qtn + qoff[i], AT2[0] + ((w & 3) * 4 + i) * 512);
  }

  // --- K prologue: producer w needs tiles w (bq0) and w+4 (bq1) ---
  short8v bq0[8], bq1[8];
  u16* KS = PB[0];   // scratch, dead before first P write
#pragma unroll 1
  for (int p = 0; p < 4; ++p) {
    if (tid < 512) stage_T(Kb, j0 + p * 64, KS, tid);
    __syncthreads();
    if (w < 4) {
      int row = (w & 1) * 32 + lj;
      if ((w >> 1) == p) {
#pragma unroll
        for (int c = 0; c < 8; ++c) bq0[c] = ld_at(KS, row, 2 * c + g);
      }
      if ((w >> 1) + 2 == p) {
#pragma unroll
        for (int c = 0; c < 8; ++c) bq1[c] = ld_at(KS, row, 2 * c + g);
      }
    }
    __syncthreads();
  }

  if (w < 4) {
    // =================== PRODUCER (64 j = tiles w, w+4) ===================
    float m0 = -1e30f, l0 = 0.f, m1 = -1e30f, l1 = 0.f;
    const int ja = w * 32 + lj;          // tile w
    const int jb = 128 + w * 32 + lj;    // tile w+4
    const int swza = ja & 7, swzb = jb & 7;

#pragma unroll 1
    for (int t = 0; t <= 32; ++t) {
      if (t < 32) {
        // issue A(t+1)
        const u16* qb = Qtn + (size_t)((t + 1) & 31) * (64 * DMODEL);
        u16* ab = AT2[(t + 1) & 1];
#pragma unroll
        for (int i = 0; i < 4; ++i)
          gload16(qb + qoff[i], ab + ((w & 3) * 4 + i) * 512);

        const u16* curAT = AT2[t & 1];
        u16* pda = PB[t & 1] + ja * PSTR;
        u16* pdb = PB[t & 1] + jb * PSTR;

#pragma unroll
        for (int s = 0; s < 2; ++s) {   // 32-i sub-tiles
          f32x16 c0 = fzero16(), c1 = fzero16();
          __builtin_amdgcn_s_setprio(1);
#pragma unroll
          for (int dc = 0; dc < 8; ++dc) {
            short8v a = ld_at(curAT, s * 32 + lj, 2 * dc + g);  // 1 read, 2 MFMA
            c0 = mfma_bf16(a, bq0[dc], c0);
            c1 = mfma_bf16(a, bq1[dc], c1);
          }
          __builtin_amdgcn_s_setprio(0);

#define SOFTPACK(C, M, L, JROW, SWZ, PD)                                     \
          {                                                                  \
            float t8[8];                                                     \
            _Pragma("unroll") for (int r = 0; r < 8; ++r)                    \
                t8[r] = fmaxf(C[r], C[r + 8]);                               \
            _Pragma("unroll") for (int r = 0; r < 4; ++r)                    \
                t8[r] = fmaxf(t8[r], t8[r + 4]);                             \
            float mx = fmaxf(fmaxf(t8[0], t8[1]), fmaxf(t8[2], t8[3]));      \
            mx = fmaxf(mx, __shfl_xor(mx, 32, 64));                          \
            float al = 1.0f;                                                 \
            if (!__all(mx <= (M) + 8.f)) {                                   \
              float mn = fmaxf((M), mx);                                     \
              al = fast_exp2((M)-mn);                                        \
              (M) = mn; (L) *= al;                                           \
            }                                                                \
            if (!g) AL[t & 1][s][JROW] = al;                                 \
            _Pragma("unroll") for (int r = 0; r < 16; ++r)                   \
                C[r] = fast_exp2(C[r] - (M));                                \
            _Pragma("unroll") for (int r = 0; r < 8; ++r)                    \
                t8[r] = C[r] + C[r + 8];                                     \
            _Pragma("unroll") for (int r = 0; r < 4; ++r)                    \
                t8[r] += t8[r + 4];                                          \
            float ps = (t8[0] + t8[1]) + (t8[2] + t8[3]);                    \
            ps += __shfl_xor(ps, 32, 64);                                    \
            (L) += ps;                                                       \
            _Pragma("unroll") for (int q = 0; q < 4; ++q) {                  \
              u32x2 val = { packbf(C[4 * q + 0], C[4 * q + 1]),              \
                            packbf(C[4 * q + 2], C[4 * q + 3]) };            \
              *reinterpret_cast<u32x2*>(                                     \
                  (PD) + (((4 * s + q) ^ (SWZ)) << 3) + 4 * g) = val;        \
            }                                                                \
          }
          SOFTPACK(c0, m0, l0, ja, swza, pda)
          SOFTPACK(c1, m1, l1, jb, swzb, pdb)
#undef SOFTPACK
        }
      }
      __syncthreads();
    }
    if (!g) { LL[ja] = l0; LL[jb] = l1; }
    __syncthreads();
  } else {
    // ========== CONSUMER (64 j = tiles 2u,2u+1; 64 d = half dh) ==========
    f32x16 oa0 = fzero16(), oa1 = fzero16(), ob0 = fzero16(), ob1 = fzero16();
    const int cw = w - 4;
    const int u = cw & 3, dh = cw >> 2;
    const int ja = 64 * u + lj;        // tile 2u
    const int jb = ja + 32;            // tile 2u+1
    const int swza = ja & 7, swzb = jb & 7;
    const int dbase = dh * 64;

#pragma unroll 1
    for (int t = 0; t <= 32; ++t) {
      if (t < 32) {
        const u16* vb = Vtn + (size_t)t * (DMODEL * 64);
        u16* vbuf = VT2[t & 1];
#pragma unroll
        for (int i = 0; i < 2; ++i)
          gload16(vb + voff[i], vbuf + (cw * 2 + i) * 512);
      }
      if (t >= 1) {
        const int tp = t - 1;
        const u16* curVT = VT2[tp & 1];
        const u16* pa = PB[tp & 1] + ja * PSTR;
        const u16* pb = PB[tp & 1] + jb * PSTR;
#pragma unroll
        for (int s = 0; s < 2; ++s) {
          float ala = AL[tp & 1][s][ja];
          float alb = AL[tp & 1][s][jb];
          if (!__all((ala == 1.0f) && (alb == 1.0f))) {
#pragma unroll
            for (int r = 0; r < 16; ++r) {
              oa0[r] *= ala; oa1[r] *= ala; ob0[r] *= alb; ob1[r] *= alb;
            }
          }
          __builtin_amdgcn_s_setprio(1);
#pragma unroll
          for (int kl = 0; kl < 2; ++kl) {
            int G = 4 * s + 2 * kl + g;
            short8v pfa = *reinterpret_cast<const short8v*>(pa + ((G ^ swza) << 3));
            short8v pfb = *reinterpret_cast<const short8v*>(pb + ((G ^ swzb) << 3));
            short8v v0 = ld_vt(curVT, dbase + lj, G);        // 1 read, 2 MFMA
            short8v v1 = ld_vt(curVT, dbase + 32 + lj, G);
            oa0 = mfma_bf16(v0, pfa, oa0);
            oa1 = mfma_bf16(v1, pfa, oa1);
            ob0 = mfma_bf16(v0, pfb, ob0);
            ob1 = mfma_bf16(v1, pfb, ob1);
          }
          __builtin_amdgcn_s_setprio(0);
        }
      }
      __syncthreads();
    }
    __syncthreads();   // matches producer LL-publish barrier
    float inva = 1.f / LL[ja];
    float invb = 1.f / LL[jb];
    u16* obase_a = Ows + ((size_t)n * SEQ + j0 + ja) * DMODEL;
    u16* obase_b = Ows + ((size_t)n * SEQ + j0 + jb) * DMODEL;
#define STORE_OT(OV, OB, DB, INV)                                         \
    {                                                                     \
      _Pragma("unroll") for (int q = 0; q < 4; ++q) {                     \
        int d0 = dbase + (DB) * 32 + 4 * g + 8 * q;                       \
        u32x2 val;                                                        \
        val.x = bfpair(OV[4 * q + 0] * (INV), OV[4 * q + 1] * (INV));     \
        val.y = bfpair(OV[4 * q + 2] * (INV), OV[4 * q + 3] * (INV));     \
        *reinterpret_cast<u32x2*>((OB) + d0) = val;                       \
      }                                                                   \
    }
    STORE_OT(oa0, obase_a, 0, inva) STORE_OT(oa1, obase_a, 1, inva)
    STORE_OT(ob0, obase_b, 0, invb) STORE_OT(ob1, obase_b, 1, invb)
#undef STORE_OT
  }
}

// ---------- projection out[b][dm][j] = sum_c Wt[dm][c] * Ows[b,c][j] ----------
__global__ __launch_bounds__(256) void proj_kernel(
    const u16* __restrict__ Ows, const u16* __restrict__ Wt, float* __restrict__ out) {
  __shared__ __align__(16) u16 BT[32 * 128];
  const int tid = threadIdx.x;
  const int w = tid >> 6, lane = tid & 63, g = lane >> 5, lj = lane & 31;
  const int b = blockIdx.x >> 6;
  const int j0 = (blockIdx.x & 63) * 32;
  f32x16 acc = fzero16();
#pragma unroll 1
  for (int h = 0; h < 16; ++h) {
    __syncthreads();
#pragma unroll
    for (int rr = 0; rr < 2; ++rr) {
      int s = tid + rr * 256;
      int r = s >> 4, cc = s & 15;
      u16x8 v = *reinterpret_cast<const u16x8*>(
          Ows + ((size_t)(b * 16 + h) * SEQ + j0 + r) * DMODEL + cc * 8);
      *reinterpret_cast<u16x8*>(BT + r * 128 + ((cc ^ (r & 7)) * 8)) = v;
    }
    __syncthreads();
#pragma unroll
    for (int kc = 0; kc < 8; ++kc) {
      short8v a = *reinterpret_cast<const short8v*>(
          Wt + (size_t)(w * 32 + lj) * SEQ + h * 128 + kc * 16 + g * 8);
      short8v bb = *reinterpret_cast<const short8v*>(
          BT + lj * 128 + (((2 * kc + g) ^ (lj & 7)) * 8));
      acc = mfma_bf16(a, bb, acc);
    }
  }
#pragma unroll
  for (int q = 0; q < 4; ++q) {
#pragma unroll
    for (int r = 0; r < 4; ++r) {
      int dm = w * 32 + 4 * g + 8 * q + r;
      out[((size_t)b * DMODEL + dm) * SEQ + j0 + lj] = acc[4 * q + r];
    }
  }
}

// ---------- host launcher ----------
extern "C" void kernel_launch(void* const* d_in, const int* in_sizes, int n_in,
                              void* d_out, int out_size, void* d_ws, size_t ws_size,
                              hipStream_t stream) {
  (void)in_sizes; (void)n_in; (void)out_size; (void)ws_size;
  const float* Q = (const float*)d_in[1];
  const float* K = (const float*)d_in[2];
  const float* V = (const float*)d_in[3];
  const float* W = (const float*)d_in[4];
  const size_t NEL = (size_t)HEADS * SEQ * DMODEL;   // 16.8M elements
  u16* Qt   = (u16*)d_ws;                // 33.5 MB
  u16* V16t = Qt + NEL;                  // 33.5 MB (tile-contiguous)
  u16* Ows  = V16t + NEL;                // 33.5 MB
  u16* Wt   = Ows + NEL;                 // 0.5 MB
  float* out = (float*)d_out;

  prep_kernel<<<dim3(4608), dim3(256), 0, stream>>>(Q, V, W, Qt, V16t, Wt);
  attn_kernel<<<dim3(512), dim3(768), 0, stream>>>(Qt, K, V16t, Ows);
  proj_kernel<<<dim3(256), dim3(256), 0, stream>>>(Ows, Wt, out);
}

// Round 10
// 251.772 us; speedup vs baseline: 1.0581x; 1.0581x over previous
//
#include <hip/hip_runtime.h>
#include <hip/hip_bf16.h>

typedef unsigned short u16;
typedef unsigned int   u32;
typedef short  short8v __attribute__((ext_vector_type(8)));
typedef u16    u16x8   __attribute__((ext_vector_type(8)));
typedef float  f32x16  __attribute__((ext_vector_type(16)));
typedef float  f32x4v  __attribute__((ext_vector_type(4)));
typedef u32    u32x2   __attribute__((ext_vector_type(2)));
typedef u32    u32x4   __attribute__((ext_vector_type(4)));

#define HEADS 64
#define DMODEL 128
#define SEQ 2048

// log2(e)/sqrt(128), folded into Qt during prep
#define SCQ 0.1275293f
// P-buffer row stride in u16 (80B)
#define PSTR 40

// ---------- helpers ----------

__device__ __forceinline__ f32x16 mfma_bf16(short8v a, short8v b, f32x16 c) {
  return __builtin_amdgcn_mfma_f32_32x32x16_bf16(a, b, c, 0, 0, 0);
}

__device__ __forceinline__ f32x16 fzero16() {
  f32x16 z;
#pragma unroll
  for (int i = 0; i < 16; ++i) z[i] = 0.f;
  return z;
}

__device__ __forceinline__ float fast_exp2(float x) {
  float r;
  asm("v_exp_f32 %0, %1" : "=v"(r) : "v"(x));   // v_exp_f32 IS exp2
  return r;
}

// round-to-nearest-even f32 -> bf16 bits
__device__ __forceinline__ u32 bfround(float x) {
  u32 u = __builtin_bit_cast(u32, x);
  u += 0x7fffu + ((u >> 16) & 1u);
  return u >> 16;
}
__device__ __forceinline__ u32 bfpair(float lo, float hi) {
  u32 a = __builtin_bit_cast(u32, lo); a += 0x7fffu + ((a >> 16) & 1u);
  u32 b = __builtin_bit_cast(u32, hi); b += 0x7fffu + ((b >> 16) & 1u);
  return (a >> 16) | (b & 0xffff0000u);
}
// hot-loop pack -> v_cvt_pk_bf16_f32 via compiler (m240)
__device__ __forceinline__ u32 packbf(float lo, float hi) {
  u32 l16 = (u32)__builtin_bit_cast(u16, __float2bfloat16(lo));
  u32 h16 = (u32)__builtin_bit_cast(u16, __float2bfloat16(hi));
  return l16 | (h16 << 16);
}

// async global->LDS, 16B/lane, dest = wave-uniform base + lane*16
typedef const __attribute__((address_space(1))) void* gp1_t;
typedef __attribute__((address_space(3))) void* lp3_t;
__device__ __forceinline__ void gload16(const u16* g, u16* l) {
  __builtin_amdgcn_global_load_lds((gp1_t)g, (lp3_t)l, 16, 0, 0);
}

// K-prologue transposing stage (512 threads): src [128 d][2048 pos] f32 ->
// LDS tile [64 pos][128 d] bf16, chunk' = chunk ^ (row & 15)
__device__ __forceinline__ void stage_T(const float* __restrict__ src, int pos0,
                                        u16* lds, int tid) {
  int ic = tid & 7;
  int d0 = (tid >> 3) * 2;
  const float* p = src + d0 * SEQ + pos0 + ic * 8;
  f32x4v xa = *reinterpret_cast<const f32x4v*>(p);
  f32x4v xb = *reinterpret_cast<const f32x4v*>(p + 4);
  f32x4v ya = *reinterpret_cast<const f32x4v*>(p + SEQ);
  f32x4v yb = *reinterpret_cast<const f32x4v*>(p + SEQ + 4);
  u32* lds32 = reinterpret_cast<u32*>(lds);
  int cc = d0 >> 3;
#pragma unroll
  for (int k = 0; k < 8; ++k) {
    int r = ic * 8 + k;
    int c2 = cc ^ (r & 15);
    float xv = (k < 4) ? xa[k & 3] : xb[k & 3];
    float yv = (k < 4) ? ya[k & 3] : yb[k & 3];
    lds32[(r * 128 + c2 * 8 + (d0 & 7)) >> 1] = bfpair(xv, yv);
  }
}

// fragment reads (ds_read_b128), undoing the XOR swizzles
__device__ __forceinline__ short8v ld_at(const u16* lds, int row, int chunk) {
  return *reinterpret_cast<const short8v*>(lds + row * 128 + ((chunk ^ (row & 15)) * 8));
}
// V tile [128 d][32 i], 4 granules/row, rot = (d ^ d>>2) & 3 (XOR)
__device__ __forceinline__ short8v ld_vt32(const u16* lds, int d, int G) {
  return *reinterpret_cast<const short8v*>(
      lds + d * 32 + ((G ^ ((d ^ (d >> 2)) & 3)) * 8));
}

// ---------- fused prep kernel ----------
// blk 0..2047:    Qt: f32 [n][128 d][2048 s] -> bf16 [n][2048 s][128 d] * SCQ
// blk 2048..4095: V:  f32 [n][128 d][2048 s] -> tile bf16 [n][it(64)][128 d][32 i]
// blk 4096..4607: Wt: f32 [2048][128] -> bf16 [128][2048]
__global__ __launch_bounds__(256) void prep_kernel(
    const float* __restrict__ Q, const float* __restrict__ V,
    const float* __restrict__ Wsrc, u16* __restrict__ Qt,
    u16* __restrict__ V16t, u16* __restrict__ Wt) {
  int blk = blockIdx.x;
  int t = threadIdx.x;
  if (blk < 2048) {
    int n = blk >> 5, pt = blk & 31;
    const float* src = Q + (size_t)n * DMODEL * SEQ;
    u16* dst = Qt + (size_t)n * SEQ * DMODEL + (size_t)pt * 64 * DMODEL;
    int pq = t & 15, dq = t >> 4;
#pragma unroll
    for (int p = 0; p < 2; ++p) {
      int d0 = (dq + 16 * p) * 4;
      const float* s0 = src + (size_t)d0 * SEQ + pt * 64 + pq * 4;
      f32x4v r0 = *reinterpret_cast<const f32x4v*>(s0);
      f32x4v r1 = *reinterpret_cast<const f32x4v*>(s0 + SEQ);
      f32x4v r2 = *reinterpret_cast<const f32x4v*>(s0 + 2 * SEQ);
      f32x4v r3 = *reinterpret_cast<const f32x4v*>(s0 + 3 * SEQ);
#pragma unroll
      for (int j = 0; j < 4; ++j) {
        u32x2 v = { bfpair(r0[j] * SCQ, r1[j] * SCQ), bfpair(r2[j] * SCQ, r3[j] * SCQ) };
        *reinterpret_cast<u32x2*>(dst + (pq * 4 + j) * DMODEL + d0) = v;
      }
    }
  } else if (blk < 4096) {
    int b2 = blk - 2048;
    int n = b2 >> 5, tp = b2 & 31;
    int tile = tp * 2 + (t >> 7);
    int d = t & 127;
    const float* src = V + ((size_t)n * DMODEL + d) * SEQ + tile * 32;
    u16* dst = V16t + (((size_t)n * 64 + tile) * DMODEL + d) * 32;
    u32x4* dst16 = reinterpret_cast<u32x4*>(dst);
#pragma unroll
    for (int c = 0; c < 4; ++c) {
      f32x4v a = *reinterpret_cast<const f32x4v*>(src + c * 8);
      f32x4v b = *reinterpret_cast<const f32x4v*>(src + c * 8 + 4);
      u32x4 v = { bfpair(a[0], a[1]), bfpair(a[2], a[3]),
                  bfpair(b[0], b[1]), bfpair(b[2], b[3]) };
      dst16[c] = v;
    }
  } else {
    int e = (blk - 4096) * 256 + t;
#pragma unroll
    for (int rr = 0; rr < 2; ++rr) {
      int o = e + rr * 131072;
      int dm = o >> 11, c = o & 2047;
      Wt[o] = (u16)bfround(Wsrc[c * 128 + dm]);
    }
  }
}

// ---------- flash attention: small-block producer/consumer ----------
// 1024 blocks = head(64) x jblock(16 x 128 j), head%8 -> XCD.
// 512 threads = 8 waves: w 0-3 producers (32 j each, 32-i steps),
//               w 4-7 consumers (dual-j: 64 j x 64 d; V-read feeds 2 MFMAs).
// 2 blocks co-resident per CU -> independent barrier groups overlap.
__global__ __launch_bounds__(512, 4) void attn_kernel(
    const u16* __restrict__ Qt, const float* __restrict__ K,
    const u16* __restrict__ V16t, u16* __restrict__ Ows) {
  __shared__ __align__(16) u16 AT2[2][32 * DMODEL];    // 2x8KB Q tiles
  __shared__ __align__(16) u16 VT2[2][DMODEL * 32];    // 2x8KB V tiles
  __shared__ __align__(16) u16 PB[2][128 * PSTR];      // 2x10KB P tiles
  __shared__ float AL[2][128];                         // alpha per j
  __shared__ float LL[128];                            // final l per j
  const int tid = threadIdx.x;
  const int w = tid >> 6;
  const int lane = tid & 63;
  const int g = lane >> 5;
  const int lj = lane & 31;
  const int p_ = blockIdx.x;
  const int n = ((p_ >> 7) << 3) | (p_ & 7);
  const int j0 = ((p_ >> 3) & 15) * 128;
  const u16* Qtn = Qt + (size_t)n * SEQ * DMODEL;
  const float* Kb = K + (size_t)n * DMODEL * SEQ;
  const u16* Vtn = V16t + (size_t)n * 64 * DMODEL * 32;

  // staging lane offsets: producers 2 gload16/A-tile, consumers 2 gload16/V-tile
  int qoff[2], voff[2];
#pragma unroll
  for (int i = 0; i < 2; ++i) {
    int idx = (w & 3) * 2 + i;
    int pos = idx * 4 + (lane >> 4);
    qoff[i] = pos * DMODEL + (((lane & 15) ^ (pos & 15)) * 8);
    int d = idx * 16 + (lane >> 2);
    voff[i] = d * 32 + (((lane & 3) ^ ((d ^ (d >> 2)) & 3)) * 8);
  }

  // prime A(0)
  if (w < 4) {
#pragma unroll
    for (int i = 0; i < 2; ++i)
      gload16(Qtn + qoff[i], AT2[0] + ((w & 3) * 2 + i) * 512);
  }

  // --- K prologue: producer w holds rows 32w+lj of the block's 128 j ---
  short8v bq[8];
  u16* KS = PB[0];   // 20KB scratch >= 16KB tile, dead before first P write
#pragma unroll 1
  for (int p = 0; p < 2; ++p) {
    stage_T(Kb, j0 + p * 64, KS, tid);
    __syncthreads();
    if (w < 4 && (w >> 1) == p) {
      int row = (w & 1) * 32 + lj;
#pragma unroll
      for (int c = 0; c < 8; ++c) bq[c] = ld_at(KS, row, 2 * c + g);
    }
    __syncthreads();
  }

  if (w < 4) {
    // =================== PRODUCER (32 j, 32-i steps) ===================
    float m_run = -1e30f, l_run = 0.f;
    const int jrow = w * 32 + lj;
    const int rotj = (jrow ^ (jrow >> 2)) & 3;

#pragma unroll 1
    for (int t = 0; t <= 64; ++t) {
      if (t < 64) {
        // issue A(t+1) (wraps to tile 0 at t=63; harmless)
        const u16* qb = Qtn + (size_t)((t + 1) & 63) * (32 * DMODEL);
        u16* ab = AT2[(t + 1) & 1];
#pragma unroll
        for (int i = 0; i < 2; ++i)
          gload16(qb + qoff[i], ab + ((w & 3) * 2 + i) * 512);

        const u16* curAT = AT2[t & 1];
        f32x16 c0 = fzero16();
        __builtin_amdgcn_s_setprio(1);
#pragma unroll
        for (int dc = 0; dc < 8; ++dc) {
          short8v a = ld_at(curAT, lj, 2 * dc + g);
          c0 = mfma_bf16(a, bq[dc], c0);
        }
        __builtin_amdgcn_s_setprio(0);

        // softmax over this step's 32 i (16 lane-local + pair-combine)
        float t8[8];
#pragma unroll
        for (int r = 0; r < 8; ++r) t8[r] = fmaxf(c0[r], c0[r + 8]);
#pragma unroll
        for (int r = 0; r < 4; ++r) t8[r] = fmaxf(t8[r], t8[r + 4]);
        float mx = fmaxf(fmaxf(t8[0], t8[1]), fmaxf(t8[2], t8[3]));
        mx = fmaxf(mx, __shfl_xor(mx, 32, 64));

        float al = 1.0f;
        if (!__all(mx <= m_run + 8.f)) {   // defer-max (T13)
          float mn = fmaxf(m_run, mx);
          al = fast_exp2(m_run - mn);
          m_run = mn;
          l_run *= al;
        }
        if (!g) AL[t & 1][jrow] = al;

#pragma unroll
        for (int r = 0; r < 16; ++r) c0[r] = fast_exp2(c0[r] - m_run);
#pragma unroll
        for (int r = 0; r < 8; ++r) t8[r] = c0[r] + c0[r + 8];
#pragma unroll
        for (int r = 0; r < 4; ++r) t8[r] += t8[r + 4];
        float ps = (t8[0] + t8[1]) + (t8[2] + t8[3]);
        ps += __shfl_xor(ps, 32, 64);
        l_run += ps;

        // pack P -> LDS: granule q (i = 8q + 4g + [0,4)), slot q^rotj, +8B*g
        u16* pdst = PB[t & 1] + jrow * PSTR;
#pragma unroll
        for (int q = 0; q < 4; ++q) {
          u32x2 val = { packbf(c0[4 * q + 0], c0[4 * q + 1]),
                        packbf(c0[4 * q + 2], c0[4 * q + 3]) };
          *reinterpret_cast<u32x2*>(pdst + ((q ^ rotj) << 3) + 4 * g) = val;
        }
      }
      __syncthreads();
    }
    if (!g) LL[jrow] = l_run;
    __syncthreads();
  } else {
    // ============ CONSUMER (dual-j 64 j x 64 d; V-read reuse 1:2) ============
    f32x16 oa0 = fzero16(), oa1 = fzero16(), ob0 = fzero16(), ob1 = fzero16();
    const int cw = w - 4;
    const int u = cw & 1, dh = cw >> 1;
    const int ja = 64 * u + lj;
    const int jb = ja + 32;
    const int rota = (ja ^ (ja >> 2)) & 3;
    const int rotb = (jb ^ (jb >> 2)) & 3;
    const int dbase = dh * 64;

#pragma unroll 1
    for (int t = 0; t <= 64; ++t) {
      if (t < 64) {
        const u16* vb = Vtn + (size_t)t * (DMODEL * 32);
        u16* vbuf = VT2[t & 1];
#pragma unroll
        for (int i = 0; i < 2; ++i)
          gload16(vb + voff[i], vbuf + (cw * 2 + i) * 512);
      }
      if (t >= 1) {
        const int tp = t - 1;
        const u16* curVT = VT2[tp & 1];
        const u16* pa = PB[tp & 1] + ja * PSTR;
        const u16* pb = PB[tp & 1] + jb * PSTR;
        float ala = AL[tp & 1][ja];
        float alb = AL[tp & 1][jb];
        if (!__all((ala == 1.0f) && (alb == 1.0f))) {
#pragma unroll
          for (int r = 0; r < 16; ++r) {
            oa0[r] *= ala; oa1[r] *= ala; ob0[r] *= alb; ob1[r] *= alb;
          }
        }
        __builtin_amdgcn_s_setprio(1);
#pragma unroll
        for (int kc = 0; kc < 2; ++kc) {
          int G = 2 * kc + g;
          short8v pfa = *reinterpret_cast<const short8v*>(pa + ((G ^ rota) << 3));
          short8v pfb = *reinterpret_cast<const short8v*>(pb + ((G ^ rotb) << 3));
          short8v v0 = ld_vt32(curVT, dbase + lj, G);        // 1 read, 2 MFMA
          short8v v1 = ld_vt32(curVT, dbase + 32 + lj, G);
          oa0 = mfma_bf16(v0, pfa, oa0);
          oa1 = mfma_bf16(v1, pfa, oa1);
          ob0 = mfma_bf16(v0, pfb, ob0);
          ob1 = mfma_bf16(v1, pfb, ob1);
        }
        __builtin_amdgcn_s_setprio(0);
      }
      __syncthreads();
    }
    __syncthreads();   // matches producer LL-publish barrier
    float inva = 1.f / LL[ja];
    float invb = 1.f / LL[jb];
    u16* obase_a = Ows + ((size_t)n * SEQ + j0 + ja) * DMODEL;
    u16* obase_b = Ows + ((size_t)n * SEQ + j0 + jb) * DMODEL;
#define STORE_OT(OV, OB, DT, INV)                                         \
    {                                                                     \
      _Pragma("unroll") for (int q = 0; q < 4; ++q) {                     \
        int d0 = dbase + (DT) * 32 + 4 * g + 8 * q;                       \
        u32x2 val;                                                        \
        val.x = bfpair(OV[4 * q + 0] * (INV), OV[4 * q + 1] * (INV));     \
        val.y = bfpair(OV[4 * q + 2] * (INV), OV[4 * q + 3] * (INV));     \
        *reinterpret_cast<u32x2*>((OB) + d0) = val;                       \
      }                                                                   \
    }
    STORE_OT(oa0, obase_a, 0, inva) STORE_OT(oa1, obase_a, 1, inva)
    STORE_OT(ob0, obase_b, 0, invb) STORE_OT(ob1, obase_b, 1, invb)
#undef STORE_OT
  }
}

// ---------- projection out[b][dm][j] = sum_c Wt[dm][c] * Ows[b,c][j] ----------
__global__ __launch_bounds__(256) void proj_kernel(
    const u16* __restrict__ Ows, const u16* __restrict__ Wt, float* __restrict__ out) {
  __shared__ __align__(16) u16 BT[32 * 128];
  const int tid = threadIdx.x;
  const int w = tid >> 6, lane = tid & 63, g = lane >> 5, lj = lane & 31;
  const int b = blockIdx.x >> 6;
  const int j0 = (blockIdx.x & 63) * 32;
  f32x16 acc = fzero16();
#pragma unroll 1
  for (int h = 0; h < 16; ++h) {
    __syncthreads();
#pragma unroll
    for (int rr = 0; rr < 2; ++rr) {
      int s = tid + rr * 256;
      int r = s >> 4, cc = s & 15;
      u16x8 v = *reinterpret_cast<const u16x8*>(
          Ows + ((size_t)(b * 16 + h) * SEQ + j0 + r) * DMODEL + cc * 8);
      *reinterpret_cast<u16x8*>(BT + r * 128 + ((cc ^ (r & 7)) * 8)) = v;
    }
    __syncthreads();
#pragma unroll
    for (int kc = 0; kc < 8; ++kc) {
      short8v a = *reinterpret_cast<const short8v*>(
          Wt + (size_t)(w * 32 + lj) * SEQ + h * 128 + kc * 16 + g * 8);
      short8v bb = *reinterpret_cast<const short8v*>(
          BT + lj * 128 + (((2 * kc + g) ^ (lj & 7)) * 8));
      acc = mfma_bf16(a, bb, acc);
    }
  }
#pragma unroll
  for (int q = 0; q < 4; ++q) {
#pragma unroll
    for (int r = 0; r < 4; ++r) {
      int dm = w * 32 + 4 * g + 8 * q + r;
      out[((size_t)b * DMODEL + dm) * SEQ + j0 + lj] = acc[4 * q + r];
    }
  }
}

// ---------- host launcher ----------
extern "C" void kernel_launch(void* const* d_in, const int* in_sizes, int n_in,
                              void* d_out, int out_size, void* d_ws, size_t ws_size,
                              hipStream_t stream) {
  (void)in_sizes; (void)n_in; (void)out_size; (void)ws_size;
  const float* Q = (const float*)d_in[1];
  const float* K = (const float*)d_in[2];
  const float* V = (const float*)d_in[3];
  const float* W = (const float*)d_in[4];
  const size_t NEL = (size_t)HEADS * SEQ * DMODEL;   // 16.8M elements
  u16* Qt   = (u16*)d_ws;                // 33.5 MB
  u16* V16t = Qt + NEL;                  // 33.5 MB (tile-contiguous 8KB tiles)
  u16* Ows  = V16t + NEL;                // 33.5 MB
  u16* Wt   = Ows + NEL;                 // 0.5 MB
  float* out = (float*)d_out;

  prep_kernel<<<dim3(4608), dim3(256), 0, stream>>>(Q, V, W, Qt, V16t, Wt);
  attn_kernel<<<dim3(1024), dim3(512), 0, stream>>>(Qt, K, V16t, Ows);
  proj_kernel<<<dim3(256), dim3(256), 0, stream>>>(Ows, Wt, out);
}

// Round 11
// 234.041 us; speedup vs baseline: 1.1383x; 1.0758x over previous
//
#include <hip/hip_runtime.h>
#include <hip/hip_bf16.h>

typedef unsigned short u16;
typedef unsigned int   u32;
typedef short  short8v __attribute__((ext_vector_type(8)));
typedef u16    u16x8   __attribute__((ext_vector_type(8)));
typedef float  f32x16  __attribute__((ext_vector_type(16)));
typedef float  f32x4v  __attribute__((ext_vector_type(4)));
typedef u32    u32x2   __attribute__((ext_vector_type(2)));
typedef u32    u32x4   __attribute__((ext_vector_type(4)));

#define HEADS 64
#define DMODEL 128
#define SEQ 2048

// log2(e)/sqrt(128), folded into Qt during prep
#define SCQ 0.1275293f
// P-buffer row stride in u16 (160B)
#define PSTR 80

// ---------- helpers ----------

__device__ __forceinline__ f32x16 mfma_bf16(short8v a, short8v b, f32x16 c) {
  return __builtin_amdgcn_mfma_f32_32x32x16_bf16(a, b, c, 0, 0, 0);
}

__device__ __forceinline__ f32x16 fzero16() {
  f32x16 z;
#pragma unroll
  for (int i = 0; i < 16; ++i) z[i] = 0.f;
  return z;
}

__device__ __forceinline__ float fast_exp2(float x) {
  float r;
  asm("v_exp_f32 %0, %1" : "=v"(r) : "v"(x));   // v_exp_f32 IS exp2
  return r;
}

// round-to-nearest-even f32 -> bf16 bits
__device__ __forceinline__ u32 bfround(float x) {
  u32 u = __builtin_bit_cast(u32, x);
  u += 0x7fffu + ((u >> 16) & 1u);
  return u >> 16;
}
__device__ __forceinline__ u32 bfpair(float lo, float hi) {
  u32 a = __builtin_bit_cast(u32, lo); a += 0x7fffu + ((a >> 16) & 1u);
  u32 b = __builtin_bit_cast(u32, hi); b += 0x7fffu + ((b >> 16) & 1u);
  return (a >> 16) | (b & 0xffff0000u);
}
// hot-loop pack -> v_cvt_pk_bf16_f32 via compiler (m240)
__device__ __forceinline__ u32 packbf(float lo, float hi) {
  u32 l16 = (u32)__builtin_bit_cast(u16, __float2bfloat16(lo));
  u32 h16 = (u32)__builtin_bit_cast(u16, __float2bfloat16(hi));
  return l16 | (h16 << 16);
}

// async global->LDS, 16B/lane, dest = wave-uniform base + lane*16
typedef const __attribute__((address_space(1))) void* gp1_t;
typedef __attribute__((address_space(3))) void* lp3_t;
__device__ __forceinline__ void gload16(const u16* g, u16* l) {
  __builtin_amdgcn_global_load_lds((gp1_t)g, (lp3_t)l, 16, 0, 0);
}

// K-prologue transposing stage (first 512 threads): src [128 d][2048 pos] f32 ->
// LDS tile [64 pos][128 d] bf16, chunk' = chunk ^ (row & 15)
__device__ __forceinline__ void stage_T(const float* __restrict__ src, int pos0,
                                        u16* lds, int tid) {
  int ic = tid & 7;
  int d0 = (tid >> 3) * 2;
  const float* p = src + d0 * SEQ + pos0 + ic * 8;
  f32x4v xa = *reinterpret_cast<const f32x4v*>(p);
  f32x4v xb = *reinterpret_cast<const f32x4v*>(p + 4);
  f32x4v ya = *reinterpret_cast<const f32x4v*>(p + SEQ);
  f32x4v yb = *reinterpret_cast<const f32x4v*>(p + SEQ + 4);
  u32* lds32 = reinterpret_cast<u32*>(lds);
  int cc = d0 >> 3;
#pragma unroll
  for (int k = 0; k < 8; ++k) {
    int r = ic * 8 + k;
    int c2 = cc ^ (r & 15);
    float xv = (k < 4) ? xa[k & 3] : xb[k & 3];
    float yv = (k < 4) ? ya[k & 3] : yb[k & 3];
    lds32[(r * 128 + c2 * 8 + (d0 & 7)) >> 1] = bfpair(xv, yv);
  }
}

// fragment reads (ds_read_b128), undoing the XOR swizzles
__device__ __forceinline__ short8v ld_at(const u16* lds, int row, int chunk) {
  return *reinterpret_cast<const short8v*>(lds + row * 128 + ((chunk ^ (row & 15)) * 8));
}
__device__ __forceinline__ short8v ld_vt(const u16* lds, int d, int chunk) {
  return *reinterpret_cast<const short8v*>(lds + d * 64 + ((chunk ^ (d & 7)) * 8));
}

// ---------- fused prep kernel ----------
__global__ __launch_bounds__(256) void prep_kernel(
    const float* __restrict__ Q, const float* __restrict__ V,
    const float* __restrict__ Wsrc, u16* __restrict__ Qt,
    u16* __restrict__ V16t, u16* __restrict__ Wt) {
  int blk = blockIdx.x;
  int t = threadIdx.x;
  if (blk < 2048) {
    int n = blk >> 5, pt = blk & 31;
    const float* src = Q + (size_t)n * DMODEL * SEQ;
    u16* dst = Qt + (size_t)n * SEQ * DMODEL + (size_t)pt * 64 * DMODEL;
    int pq = t & 15, dq = t >> 4;
#pragma unroll
    for (int p = 0; p < 2; ++p) {
      int d0 = (dq + 16 * p) * 4;
      const float* s0 = src + (size_t)d0 * SEQ + pt * 64 + pq * 4;
      f32x4v r0 = *reinterpret_cast<const f32x4v*>(s0);
      f32x4v r1 = *reinterpret_cast<const f32x4v*>(s0 + SEQ);
      f32x4v r2 = *reinterpret_cast<const f32x4v*>(s0 + 2 * SEQ);
      f32x4v r3 = *reinterpret_cast<const f32x4v*>(s0 + 3 * SEQ);
#pragma unroll
      for (int j = 0; j < 4; ++j) {
        u32x2 v = { bfpair(r0[j] * SCQ, r1[j] * SCQ), bfpair(r2[j] * SCQ, r3[j] * SCQ) };
        *reinterpret_cast<u32x2*>(dst + (pq * 4 + j) * DMODEL + d0) = v;
      }
    }
  } else if (blk < 4096) {
    int b2 = blk - 2048;
    int n = b2 >> 5, it = b2 & 31;
    int s8 = (t & 7) * 8;
    const float* src = V + (size_t)n * DMODEL * SEQ + it * 64 + s8;
    u16* dst = V16t + (size_t)b2 * DMODEL * 64 + s8;
#pragma unroll
    for (int rr = 0; rr < 4; ++rr) {
      int d = (t >> 3) + 32 * rr;
      const float* p = src + (size_t)d * SEQ;
      f32x4v a = *reinterpret_cast<const f32x4v*>(p);
      f32x4v b = *reinterpret_cast<const f32x4v*>(p + 4);
      u32x4 v = { bfpair(a[0], a[1]), bfpair(a[2], a[3]),
                  bfpair(b[0], b[1]), bfpair(b[2], b[3]) };
      *reinterpret_cast<u32x4*>(dst + d * 64) = v;
    }
  } else {
    int e = (blk - 4096) * 256 + t;
#pragma unroll
    for (int rr = 0; rr < 2; ++rr) {
      int o = e + rr * 131072;
      int dm = o >> 11, c = o & 2047;
      Wt[o] = (u16)bfround(Wsrc[c * 128 + dm]);
    }
  }
}

// ---------- flash attention, wave-specialized producer / d-split consumer ----
// 512 blocks = head(64) x jblock(8 x 256 j), head%8 -> XCD.
// 1024 threads = 16 waves:
//   w 0-7  producers: QK^T + softmax for j-slice w (32 j), 64-i steps
//   w 8-15 consumers: PV for 64 j x 64 d: ju=(w-8)&3 selects j-pair
//          {64ju..+31, 64ju+32..+63}; dh=(w-8)>>2 selects d-half.
//          Each V-row is read by 4 waves (was 8): LDS reads/step 288->256.
__global__ __launch_bounds__(1024, 4) void attn_kernel(
    const u16* __restrict__ Qt, const float* __restrict__ K,
    const u16* __restrict__ V16t, u16* __restrict__ Ows) {
  __shared__ __align__(16) u16 AT2[2][64 * DMODEL];    // 2x16KB Q tiles
  __shared__ __align__(16) u16 VT2[2][DMODEL * 64];    // 2x16KB V tiles
  __shared__ __align__(16) u16 PB[2][256 * PSTR];      // 2x40KB P tiles
  __shared__ float AL[2][256];                         // alpha per j
  __shared__ float LL[256];                            // final l per j
  const int tid = threadIdx.x;
  const int w = tid >> 6;
  const int lane = tid & 63;
  const int g = lane >> 5;
  const int lj = lane & 31;
  const int p_ = blockIdx.x;
  const int n = ((p_ >> 6) << 3) | (p_ & 7);
  const int j0 = ((p_ >> 3) & 7) * 256;
  const u16* Qtn = Qt + (size_t)n * SEQ * DMODEL;
  const float* Kb = K + (size_t)n * DMODEL * SEQ;
  const u16* Vtn = V16t + (size_t)n * 32 * DMODEL * 64;

  // staging lane offsets (2 gload16 per wave per tile; pre-swizzled source)
  int qoff[2], voff[2];
#pragma unroll
  for (int i = 0; i < 2; ++i) {
    int idx = (w & 7) * 2 + i;
    int pos = idx * 4 + (lane >> 4);
    qoff[i] = pos * DMODEL + (((lane & 15) ^ (pos & 15)) * 8);
    int d = idx * 8 + (lane >> 3);
    voff[i] = d * 64 + (((lane & 7) ^ (d & 7)) * 8);
  }

  // ---- shared prologue: K rows for producers; prime A(0) ----
  if (w < 8) {
    const u16* qb = Qtn;  // tile 0
#pragma unroll
    for (int i = 0; i < 2; ++i)
      gload16(qb + qoff[i], AT2[0] + ((w & 7) * 2 + i) * 512);
  }
  short8v bq[8];
  u16* KS = PB[0];   // scratch, free before main loop
#pragma unroll 1
  for (int p = 0; p < 4; ++p) {
    if (tid < 512) stage_T(Kb, j0 + p * 64, KS, tid);
    __syncthreads();
    if (w < 8 && (w >> 1) == p) {
      int row = (w & 1) * 32 + lj;
#pragma unroll
      for (int c = 0; c < 8; ++c) bq[c] = ld_at(KS, row, 2 * c + g);
    }
    __syncthreads();
  }

  if (w < 8) {
    // =================== PRODUCER (R8, unchanged) ===================
    float m_run = -1e30f, l_run = 0.f;
    const int prow = w * 32 + lj;
    u16* const prowbase0 = PB[0] + prow * PSTR;
    u16* const prowbase1 = PB[1] + prow * PSTR;
    const int swz = prow & 7;

#pragma unroll 1
    for (int t = 0; t <= 32; ++t) {
      if (t < 32) {
        // issue A(t+1)
        const u16* qb = Qtn + (size_t)((t + 1) & 31) * (64 * DMODEL);
        u16* ab = AT2[(t + 1) & 1];
#pragma unroll
        for (int i = 0; i < 2; ++i)
          gload16(qb + qoff[i], ab + ((w & 7) * 2 + i) * 512);

        const u16* curAT = AT2[t & 1];
        f32x16 c0 = fzero16(), c1 = fzero16();
        __builtin_amdgcn_s_setprio(1);
#pragma unroll
        for (int dc = 0; dc < 8; ++dc) {
          short8v a0 = ld_at(curAT, lj, 2 * dc + g);
          short8v a1 = ld_at(curAT, 32 + lj, 2 * dc + g);
          c0 = mfma_bf16(a0, bq[dc], c0);
          c1 = mfma_bf16(a1, bq[dc], c1);
        }
        __builtin_amdgcn_s_setprio(0);

        // tree max over 32 lane-local values, then pair-combine
        float m8[8];
#pragma unroll
        for (int r = 0; r < 8; ++r)
          m8[r] = fmaxf(fmaxf(c0[r], c0[r + 8]), fmaxf(c1[r], c1[r + 8]));
#pragma unroll
        for (int r = 0; r < 4; ++r) m8[r] = fmaxf(m8[r], m8[r + 4]);
        float mx = fmaxf(fmaxf(m8[0], m8[1]), fmaxf(m8[2], m8[3]));
        mx = fmaxf(mx, __shfl_xor(mx, 32, 64));

        float al = 1.0f;
        if (!__all(mx <= m_run + 8.f)) {   // defer-max (T13)
          float mn = fmaxf(m_run, mx);
          al = fast_exp2(m_run - mn);
          m_run = mn;
          l_run *= al;
        }
        if (!g) AL[t & 1][prow] = al;

#pragma unroll
        for (int r = 0; r < 16; ++r) c0[r] = fast_exp2(c0[r] - m_run);
#pragma unroll
        for (int r = 0; r < 16; ++r) c1[r] = fast_exp2(c1[r] - m_run);
        float s8[8];
#pragma unroll
        for (int r = 0; r < 8; ++r) s8[r] = (c0[r] + c0[r + 8]) + (c1[r] + c1[r + 8]);
#pragma unroll
        for (int r = 0; r < 4; ++r) s8[r] += s8[r + 4];
        float ps = (s8[0] + s8[1]) + (s8[2] + s8[3]);
        ps += __shfl_xor(ps, 32, 64);
        l_run += ps;

        // pack P -> LDS. c half H covers i = 32H + 8q + 4g + [0,4): granule
        // G = q + 4H, swizzled G^swz, intra-granule u16 offset 4g.
        u16* pdst = (t & 1) ? prowbase1 : prowbase0;
#pragma unroll
        for (int half = 0; half < 2; ++half) {
#pragma unroll
          for (int q = 0; q < 4; ++q) {
            u32x2 val;
            val.x = half ? packbf(c1[4 * q + 0], c1[4 * q + 1])
                         : packbf(c0[4 * q + 0], c0[4 * q + 1]);
            val.y = half ? packbf(c1[4 * q + 2], c1[4 * q + 3])
                         : packbf(c0[4 * q + 2], c0[4 * q + 3]);
            int G = q + 4 * half;
            *reinterpret_cast<u32x2*>(pdst + ((G ^ swz) << 3) + 4 * g) = val;
          }
        }
      }
      __syncthreads();
    }
    if (!g) LL[prow] = l_run;
    __syncthreads();
    // producer done (no store)
  } else {
    // ============ CONSUMER (d-split: 64 j x 64 d, V-read reuse 1:2) ============
    f32x16 oa0 = fzero16(), oa1 = fzero16(), ob0 = fzero16(), ob1 = fzero16();
    const int cw = w - 8;
    const int ju = cw & 3, dh = cw >> 2;
    const int ja = 64 * ju + lj;
    const int jb = ja + 32;
    const int swza = ja & 7, swzb = jb & 7;
    const int dbase = dh * 64;

#pragma unroll 1
    for (int t = 0; t <= 32; ++t) {
      if (t < 32) {
        // issue V(t)
        const u16* vb = Vtn + (size_t)t * (DMODEL * 64);
        u16* vbuf = VT2[t & 1];
#pragma unroll
        for (int i = 0; i < 2; ++i)
          gload16(vb + voff[i], vbuf + (cw * 2 + i) * 512);
      }
      if (t >= 1) {
        const int tp = t - 1;
        const u16* curVT = VT2[tp & 1];
        const u16* pa = PB[tp & 1] + ja * PSTR;
        const u16* pb = PB[tp & 1] + jb * PSTR;
        float ala = AL[tp & 1][ja];
        float alb = AL[tp & 1][jb];
        if (!__all((ala == 1.0f) && (alb == 1.0f))) {
#pragma unroll
          for (int r = 0; r < 16; ++r) {
            oa0[r] *= ala; oa1[r] *= ala; ob0[r] *= alb; ob1[r] *= alb;
          }
        }
        __builtin_amdgcn_s_setprio(1);
#pragma unroll
        for (int kc = 0; kc < 4; ++kc) {
          int G = 2 * kc + g;
          short8v pfa = *reinterpret_cast<const short8v*>(pa + ((G ^ swza) << 3));
          short8v pfb = *reinterpret_cast<const short8v*>(pb + ((G ^ swzb) << 3));
          short8v v0 = ld_vt(curVT, dbase + lj, G);        // 1 read, 2 MFMA
          short8v v1 = ld_vt(curVT, dbase + 32 + lj, G);
          oa0 = mfma_bf16(v0, pfa, oa0);
          oa1 = mfma_bf16(v1, pfa, oa1);
          ob0 = mfma_bf16(v0, pfb, ob0);
          ob1 = mfma_bf16(v1, pfb, ob1);
        }
        __builtin_amdgcn_s_setprio(0);
      }
      __syncthreads();
    }
    __syncthreads();   // matches producer's LL-publish barrier
    float inva = 1.f / LL[ja];
    float invb = 1.f / LL[jb];
    u16* obase_a = Ows + ((size_t)n * SEQ + j0 + ja) * DMODEL;
    u16* obase_b = Ows + ((size_t)n * SEQ + j0 + jb) * DMODEL;
#define STORE_OT(OV, OB, DT, INV)                                         \
    {                                                                     \
      _Pragma("unroll") for (int q = 0; q < 4; ++q) {                     \
        int d0 = dbase + (DT) * 32 + 4 * g + 8 * q;                       \
        u32x2 val;                                                        \
        val.x = bfpair(OV[4 * q + 0] * (INV), OV[4 * q + 1] * (INV));     \
        val.y = bfpair(OV[4 * q + 2] * (INV), OV[4 * q + 3] * (INV));     \
        *reinterpret_cast<u32x2*>((OB) + d0) = val;                       \
      }                                                                   \
    }
    STORE_OT(oa0, obase_a, 0, inva) STORE_OT(oa1, obase_a, 1, inva)
    STORE_OT(ob0, obase_b, 0, invb) STORE_OT(ob1, obase_b, 1, invb)
#undef STORE_OT
  }
}

// ---------- projection out[b][dm][j] = sum_c Wt[dm][c] * Ows[b,c][j] ----------
__global__ __launch_bounds__(256) void proj_kernel(
    const u16* __restrict__ Ows, const u16* __restrict__ Wt, float* __restrict__ out) {
  __shared__ __align__(16) u16 BT[32 * 128];
  const int tid = threadIdx.x;
  const int w = tid >> 6, lane = tid & 63, g = lane >> 5, lj = lane & 31;
  const int b = blockIdx.x >> 6;
  const int j0 = (blockIdx.x & 63) * 32;
  f32x16 acc = fzero16();
#pragma unroll 1
  for (int h = 0; h < 16; ++h) {
    __syncthreads();
#pragma unroll
    for (int rr = 0; rr < 2; ++rr) {
      int s = tid + rr * 256;
      int r = s >> 4, cc = s & 15;
      u16x8 v = *reinterpret_cast<const u16x8*>(
          Ows + ((size_t)(b * 16 + h) * SEQ + j0 + r) * DMODEL + cc * 8);
      *reinterpret_cast<u16x8*>(BT + r * 128 + ((cc ^ (r & 7)) * 8)) = v;
    }
    __syncthreads();
#pragma unroll
    for (int kc = 0; kc < 8; ++kc) {
      short8v a = *reinterpret_cast<const short8v*>(
          Wt + (size_t)(w * 32 + lj) * SEQ + h * 128 + kc * 16 + g * 8);
      short8v bb = *reinterpret_cast<const short8v*>(
          BT + lj * 128 + (((2 * kc + g) ^ (lj & 7)) * 8));
      acc = mfma_bf16(a, bb, acc);
    }
  }
#pragma unroll
  for (int q = 0; q < 4; ++q) {
#pragma unroll
    for (int r = 0; r < 4; ++r) {
      int dm = w * 32 + 4 * g + 8 * q + r;
      out[((size_t)b * DMODEL + dm) * SEQ + j0 + lj] = acc[4 * q + r];
    }
  }
}

// ---------- host launcher ----------
extern "C" void kernel_launch(void* const* d_in, const int* in_sizes, int n_in,
                              void* d_out, int out_size, void* d_ws, size_t ws_size,
                              hipStream_t stream) {
  (void)in_sizes; (void)n_in; (void)out_size; (void)ws_size;
  const float* Q = (const float*)d_in[1];
  const float* K = (const float*)d_in[2];
  const float* V = (const float*)d_in[3];
  const float* W = (const float*)d_in[4];
  const size_t NEL = (size_t)HEADS * SEQ * DMODEL;   // 16.8M elements
  u16* Qt   = (u16*)d_ws;                // 33.5 MB
  u16* V16t = Qt + NEL;                  // 33.5 MB (tile-contiguous)
  u16* Ows  = V16t + NEL;                // 33.5 MB
  u16* Wt   = Ows + NEL;                 // 0.5 MB
  float* out = (float*)d_out;

  prep_kernel<<<dim3(4608), dim3(256), 0, stream>>>(Q, V, W, Qt, V16t, Wt);
  attn_kernel<<<dim3(512), dim3(1024), 0, stream>>>(Qt, K, V16t, Ows);
  proj_kernel<<<dim3(256), dim3(256), 0, stream>>>(Ows, Wt, out);
}